// Round 5
// baseline (628.055 us; speedup 1.0000x reference)
//
#include <hip/hip_runtime.h>

// Problem constants: B=32, N=2048, D=512, O=2
#define BB 32
#define NN 2048
#define DD 512
#define CC 64            // chunks along N
#define LL 32            // NN/CC steps per chunk
#define D2 (DD/2)        // 256 float2 columns per row

typedef float vf2 __attribute__((ext_vector_type(2)));
typedef unsigned long long u64;

// Agent-scope 8B atomics (bypass XCD-local caching; cross-XCD safe)
__device__ __forceinline__ void ast64(u64* p, vf2 v) {
    u64 u; __builtin_memcpy(&u, &v, 8);
    __hip_atomic_store(p, u, __ATOMIC_RELAXED, __HIP_MEMORY_SCOPE_AGENT);
}
__device__ __forceinline__ vf2 ald64(const u64* p) {
    u64 u = __hip_atomic_load(p, __ATOMIC_RELAXED, __HIP_MEMORY_SCOPE_AGENT);
    vf2 v; __builtin_memcpy(&v, &u, 8); return v;
}

// State recurrence:
//   m0' = a0*m0 + g ; m1' = a1*m1 + m0' ; w' = e*w + c0*g + c1*m0' + c2*m1'
// Per-step matrix M_t (lower-tri, gate-only); chunk matrix P = prod M_t.
// w_true[t] = w_local[t] + q_t . s_init, q_t = bottom row of prefix product.

__global__ __launch_bounds__(256) void fused_scan(
    const float* __restrict__ grad,   // (B,N,D)
    const float* __restrict__ am,     // (2,B,N)
    const float* __restrict__ cm,     // (3,B,N)
    const float* __restrict__ dec,    // (B,N)
    const float* __restrict__ Wt,     // (B,D)
    const float* __restrict__ lm,     // (2,B,D)
    int*  __restrict__ flags,         // BB*CC : 0 none, 1 partial, 2 inclusive
    u64*  __restrict__ Pbuf,          // BB*CC*3 : (p00,p10)(p11,p20)(p21,p22)
    u64*  __restrict__ endb,          // BB*CC*3*D2 local endpoints
    u64*  __restrict__ incb,          // BB*CC*3*D2 inclusive endpoints
    float* __restrict__ out)          // update (B,N+1,D) then next_last (2,B,D)
{
    const int id  = blockIdx.x;
    const int b   = id & (BB - 1);   // batch fastest -> chunk-0 cohort dispatches first
    const int c   = id / BB;         // same-b chain has id-stride 32 -> same XCD
    const int tid = threadIdx.x;

    __shared__ float lds_g[LL * DD];   // grad chunk, overwritten with w_local
    __shared__ float lds_q[LL * 3];    // per-step bottom row q_t (uniform)

    // ---- stage grad chunk into LDS (float4, coalesced) ----
    {
        const float4* gs = (const float4*)(grad + ((size_t)(b * NN + c * LL)) * DD);
        float4* ld = (float4*)lds_g;
        #pragma unroll
        for (int k = 0; k < (LL * DD / 4) / 256; ++k)   // 16 iters
            ld[k * 256 + tid] = gs[k * 256 + tid];
    }

    const float* a0p = am + (size_t)(0 * BB + b) * NN + c * LL;
    const float* a1p = am + (size_t)(1 * BB + b) * NN + c * LL;
    const float* c0p = cm + (size_t)(0 * BB + b) * NN + c * LL;
    const float* c1p = cm + (size_t)(1 * BB + b) * NN + c * LL;
    const float* c2p = cm + (size_t)(2 * BB + b) * NN + c * LL;
    const float* dp  = dec + (size_t)b * NN + c * LL;

    __syncthreads();

    // ---- local scan from zero + chunk matrix ----
    vf2 m0 = {0.f, 0.f}, m1 = {0.f, 0.f}, w = {0.f, 0.f};
    float p00 = 1.f, p10 = 0.f, p11 = 1.f, p20 = 0.f, p21 = 0.f, p22 = 1.f;
    #pragma unroll 8
    for (int t = 0; t < LL; ++t) {
        const float a0 = a0p[t], a1 = a1p[t];
        const float c0 = c0p[t], c1 = c1p[t], c2 = c2p[t];
        const float e  = 1.0f - dp[t];
        vf2 g = *(const vf2*)&lds_g[t * DD + 2 * tid];

        m0.x = fmaf(a0, m0.x, g.x);  m0.y = fmaf(a0, m0.y, g.y);
        m1.x = fmaf(a1, m1.x, m0.x); m1.y = fmaf(a1, m1.y, m0.y);
        w.x = fmaf(e, w.x, fmaf(c0, g.x, fmaf(c1, m0.x, c2 * m1.x)));
        w.y = fmaf(e, w.y, fmaf(c0, g.y, fmaf(c1, m0.y, c2 * m1.y)));

        *(vf2*)&lds_g[t * DD + 2 * tid] = w;   // stash w_local in place

        const float k0 = (c1 + c2) * a0;
        const float k1 = c2 * a1;
        const float n00 = a0 * p00;
        const float n10 = fmaf(a0, p00, a1 * p10);
        const float n11 = a1 * p11;
        const float n20 = fmaf(k0, p00, fmaf(k1, p10, e * p20));
        const float n21 = fmaf(k1, p11, e * p21);
        const float n22 = e * p22;
        p00 = n00; p10 = n10; p11 = n11; p20 = n20; p21 = n21; p22 = n22;

        if (tid == 0) {
            lds_q[t * 3 + 0] = p20; lds_q[t * 3 + 1] = p21; lds_q[t * 3 + 2] = p22;
        }
    }

    const int    cid = b * CC + c;
    const size_t vb  = (size_t)cid * 3 * D2;

    // ---- publish partial (c>0) so successors can proceed ----
    if (c > 0) {
        ast64(&endb[vb + 0 * D2 + tid], m0);
        ast64(&endb[vb + 1 * D2 + tid], m1);
        ast64(&endb[vb + 2 * D2 + tid], w);
        if (tid == 0) {
            vf2 q;
            q.x = p00; q.y = p10; ast64(&Pbuf[(size_t)cid * 3 + 0], q);
            q.x = p11; q.y = p20; ast64(&Pbuf[(size_t)cid * 3 + 1], q);
            q.x = p21; q.y = p22; ast64(&Pbuf[(size_t)cid * 3 + 2], q);
        }
        __syncthreads();   // all data stores retired before flag
        if (tid == 0)
            __hip_atomic_store(&flags[cid], 1, __ATOMIC_RELEASE, __HIP_MEMORY_SCOPE_AGENT);
    }

    // ---- obtain s_init ----
    vf2 s0, s1, s2;
    if (c == 0) {
        s0 = *(const vf2*)&lm[(size_t)(0 * BB + b) * DD + 2 * tid];
        s1 = *(const vf2*)&lm[(size_t)(1 * BB + b) * DD + 2 * tid];
        s2 = *(const vf2*)&Wt[(size_t)b * DD + 2 * tid];
    } else {
        // decoupled lookback: combine predecessor partials until an inclusive
        vf2 A0 = {0.f, 0.f}, A1 = {0.f, 0.f}, A2 = {0.f, 0.f};
        float q00 = 1.f, q10 = 0.f, q11 = 1.f, q20 = 0.f, q21 = 0.f, q22 = 1.f;
        int j = c - 1;
        for (;;) {
            const int fidx = b * CC + j;
            int f;
            for (;;) {
                f = __hip_atomic_load(&flags[fidx], __ATOMIC_ACQUIRE, __HIP_MEMORY_SCOPE_AGENT);
                if (f != 0) break;
                __builtin_amdgcn_s_sleep(1);
            }
            const size_t jb = (size_t)fidx * 3 * D2;
            const u64* src = (f == 2) ? incb : endb;
            vf2 v0 = ald64(&src[jb + 0 * D2 + tid]);
            vf2 v1 = ald64(&src[jb + 1 * D2 + tid]);
            vf2 v2 = ald64(&src[jb + 2 * D2 + tid]);
            A0.x = fmaf(q00, v0.x, A0.x);
            A0.y = fmaf(q00, v0.y, A0.y);
            A1.x = fmaf(q10, v0.x, fmaf(q11, v1.x, A1.x));
            A1.y = fmaf(q10, v0.y, fmaf(q11, v1.y, A1.y));
            A2.x = fmaf(q20, v0.x, fmaf(q21, v1.x, fmaf(q22, v2.x, A2.x)));
            A2.y = fmaf(q20, v0.y, fmaf(q21, v1.y, fmaf(q22, v2.y, A2.y)));
            if (f == 2) break;
            vf2 P0 = ald64(&Pbuf[(size_t)fidx * 3 + 0]);
            vf2 P1 = ald64(&Pbuf[(size_t)fidx * 3 + 1]);
            vf2 P2 = ald64(&Pbuf[(size_t)fidx * 3 + 2]);
            const float b00 = P0.x, b10 = P0.y, b11 = P1.x;
            const float b20 = P1.y, b21 = P2.x, b22 = P2.y;
            const float r00 = q00 * b00;
            const float r10 = fmaf(q10, b00, q11 * b10);
            const float r11 = q11 * b11;
            const float r20 = fmaf(q20, b00, fmaf(q21, b10, q22 * b20));
            const float r21 = fmaf(q21, b11, q22 * b21);
            const float r22 = q22 * b22;
            q00 = r00; q10 = r10; q11 = r11; q20 = r20; q21 = r21; q22 = r22;
            --j;   // j>=0 guaranteed: flags[b][0] only ever becomes 2
        }
        s0 = A0; s1 = A1; s2 = A2;
    }

    // ---- inclusive endpoint (also = final state for last chunk) ----
    vf2 i0, i1, i2;
    i0.x = fmaf(p00, s0.x, m0.x);
    i0.y = fmaf(p00, s0.y, m0.y);
    i1.x = fmaf(p10, s0.x, fmaf(p11, s1.x, m1.x));
    i1.y = fmaf(p10, s0.y, fmaf(p11, s1.y, m1.y));
    i2.x = fmaf(p20, s0.x, fmaf(p21, s1.x, fmaf(p22, s2.x, w.x)));
    i2.y = fmaf(p20, s0.y, fmaf(p21, s1.y, fmaf(p22, s2.y, w.y)));

    if (c < CC - 1) {
        ast64(&incb[vb + 0 * D2 + tid], i0);
        ast64(&incb[vb + 1 * D2 + tid], i1);
        ast64(&incb[vb + 2 * D2 + tid], i2);
        __syncthreads();
        if (tid == 0)
            __hip_atomic_store(&flags[cid], 2, __ATOMIC_RELEASE, __HIP_MEMORY_SCOPE_AGENT);
    } else {
        __syncthreads();   // lds_q / lds_g visibility before phase E on this path
    }

    // ---- phase E: w_true[t] = w_local[t] + q_t . s_init ; NT-stream to out ----
    vf2* out2 = (vf2*)out;
    const size_t orow = (size_t)b * (NN + 1);
    if (c == 0)
        __builtin_nontemporal_store(s2, &out2[orow * D2 + tid]);   // update[b][0]=W_t

    #pragma unroll 8
    for (int t = 0; t < LL; ++t) {
        vf2 wl = *(const vf2*)&lds_g[t * DD + 2 * tid];
        const float qa = lds_q[t * 3 + 0], qb = lds_q[t * 3 + 1], qc = lds_q[t * 3 + 2];
        vf2 wt;
        wt.x = fmaf(qa, s0.x, fmaf(qb, s1.x, fmaf(qc, s2.x, wl.x)));
        wt.y = fmaf(qa, s0.y, fmaf(qb, s1.y, fmaf(qc, s2.y, wl.y)));
        __builtin_nontemporal_store(wt, &out2[(orow + (size_t)(c * LL + t + 1)) * D2 + tid]);
    }

    if (c == CC - 1) {
        // next_last_momentum (2,B,D) = final m0, m1 (= inclusive i0, i1)
        const size_t nl = (size_t)BB * (NN + 1) * D2;
        __builtin_nontemporal_store(i0, &out2[nl + (size_t)(0 * BB + b) * D2 + tid]);
        __builtin_nontemporal_store(i1, &out2[nl + (size_t)(1 * BB + b) * D2 + tid]);
    }
}

extern "C" void kernel_launch(void* const* d_in, const int* in_sizes, int n_in,
                              void* d_out, int out_size, void* d_ws, size_t ws_size,
                              hipStream_t stream) {
    const float* Wt   = (const float*)d_in[0];   // (B,D)
    // d_in[1] = x_t, unused
    const float* grad = (const float*)d_in[2];   // (B,N,D)
    const float* lm   = (const float*)d_in[3];   // (2,B,D)
    const float* am   = (const float*)d_in[4];   // (2,B,N,1)
    const float* cm   = (const float*)d_in[5];   // (3,B,N)
    const float* dec  = (const float*)d_in[6];   // (B,N,1)
    float* out = (float*)d_out;

    // ws layout: flags (8 KB) | Pbuf (48 KB) | endb (12.6 MB) | incb (12.6 MB)
    char* ws = (char*)d_ws;
    int* flags = (int*)ws;
    u64* Pbuf  = (u64*)(ws + (size_t)BB * CC * sizeof(int));
    u64* endb  = (u64*)(ws + (size_t)BB * CC * sizeof(int)
                           + (size_t)BB * CC * 3 * sizeof(u64));
    u64* incb  = endb + (size_t)BB * CC * 3 * D2;

    hipMemsetAsync(flags, 0, (size_t)BB * CC * sizeof(int), stream);
    fused_scan<<<BB * CC, 256, 0, stream>>>(grad, am, cm, dec, Wt, lm,
                                            flags, Pbuf, endb, incb, out);
}

// Round 6
// 94.439 us; speedup vs baseline: 6.6504x; 6.6504x over previous
//
#include <hip/hip_runtime.h>

// Problem constants: B=32, N=2048, D=512, O=2
#define BB 32
#define NN 2048
#define DD 512
#define CC 64            // chunks along N
#define LL 32            // steps per chunk
#define HC 32            // chunks per half (CC/2)
#define D4 128           // float4 columns per row

typedef float vf4 __attribute__((ext_vector_type(4)));

// Recurrence: m0'=a0*m0+g ; m1'=a1*m1+m0' ; w'=e*w + c0*g + c1*m0' + c2*m1'
// Per-step matrix (lower-tri, gate-only); chunk matrix P = prod M_t (6 scalars).

// ---------------- Pass 1: per-chunk local scan (zero init) + chunk matrix ----------------
__global__ __launch_bounds__(128) void pass1_local(
    const float* __restrict__ grad,   // (B,N,D)
    const float* __restrict__ am,     // (2,B,N)
    const float* __restrict__ cm,     // (3,B,N)
    const float* __restrict__ dec,    // (B,N)
    float* __restrict__ Mtot,         // (B,CC,6)
    float* __restrict__ local_end,    // (B,CC,3,D)
    int h)                            // half index
{
    const int c = blockIdx.x + h * HC;
    const int b = blockIdx.y;
    const int tid = threadIdx.x;      // float4 lane; d = 4*tid
    const vf4* g4 = (const vf4*)grad;

    const float* a0p = am + (size_t)(0 * BB + b) * NN;
    const float* a1p = am + (size_t)(1 * BB + b) * NN;
    const float* c0p = cm + (size_t)(0 * BB + b) * NN;
    const float* c1p = cm + (size_t)(1 * BB + b) * NN;
    const float* c2p = cm + (size_t)(2 * BB + b) * NN;
    const float* dp  = dec + (size_t)b * NN;

    vf4 m0 = {0.f, 0.f, 0.f, 0.f}, m1 = m0, w = m0;
    float p00 = 1.f, p10 = 0.f, p11 = 1.f, p20 = 0.f, p21 = 0.f, p22 = 1.f;

    const int t0 = c * LL;
    #pragma unroll 8
    for (int t = t0; t < t0 + LL; ++t) {
        const float a0 = a0p[t], a1 = a1p[t];
        const float c0 = c0p[t], c1 = c1p[t], c2 = c2p[t];
        const float e  = 1.0f - dp[t];
        const vf4 g = g4[(size_t)(b * NN + t) * D4 + tid];

        m0 = a0 * m0 + g;
        m1 = a1 * m1 + m0;
        w  = e * w + c0 * g + c1 * m0 + c2 * m1;

        const float k0 = (c1 + c2) * a0;
        const float k1 = c2 * a1;
        const float n00 = a0 * p00;
        const float n10 = fmaf(a0, p00, a1 * p10);
        const float n11 = a1 * p11;
        const float n20 = fmaf(k0, p00, fmaf(k1, p10, e * p20));
        const float n21 = fmaf(k1, p11, e * p21);
        const float n22 = e * p22;
        p00 = n00; p10 = n10; p11 = n11; p20 = n20; p21 = n21; p22 = n22;
    }

    vf4* le = (vf4*)local_end;
    const size_t base = (size_t)(b * CC + c) * 3 * D4;
    le[base + 0 * D4 + tid] = m0;
    le[base + 1 * D4 + tid] = m1;
    le[base + 2 * D4 + tid] = w;

    if (tid == 0) {
        float* mt = Mtot + (size_t)(b * CC + c) * 6;
        mt[0] = p00; mt[1] = p10; mt[2] = p11;
        mt[3] = p20; mt[4] = p21; mt[5] = p22;
    }
}

// ---------------- Pass 2: carry scan over this half's chunks ----------------
__global__ __launch_bounds__(128) void pass2_carry(
    const float* __restrict__ Wt,        // (B,D)
    const float* __restrict__ lm,        // (2,B,D)
    const float* __restrict__ Mtot,      // (B,CC,6)
    const float* __restrict__ local_end, // (B,CC,3,D)
    float* __restrict__ carry,           // (B,CC,3,D) = s_init per chunk
    float* __restrict__ boundary,        // (3,B,D) inter-half state
    float* __restrict__ out,             // update (B,N+1,D) then next_last (2,B,D)
    int h)
{
    const int b = blockIdx.x;
    const int tid = threadIdx.x;

    vf4 s0, s1, s2;
    vf4* out4 = (vf4*)out;
    vf4* bd = (vf4*)boundary;

    if (h == 0) {
        s0 = ((const vf4*)lm)[(size_t)(0 * BB + b) * D4 + tid];
        s1 = ((const vf4*)lm)[(size_t)(1 * BB + b) * D4 + tid];
        s2 = ((const vf4*)Wt)[(size_t)b * D4 + tid];
        // update[b][0][:] = W_t
        __builtin_nontemporal_store(s2, &out4[(size_t)(b * (NN + 1)) * D4 + tid]);
    } else {
        s0 = bd[(size_t)(0 * BB + b) * D4 + tid];
        s1 = bd[(size_t)(1 * BB + b) * D4 + tid];
        s2 = bd[(size_t)(2 * BB + b) * D4 + tid];
    }

    vf4* cy = (vf4*)carry;
    const vf4* le = (const vf4*)local_end;

    const int cbeg = h * HC;
    for (int c = cbeg; c < cbeg + HC; ++c) {
        const size_t base = (size_t)(b * CC + c) * 3 * D4;
        cy[base + 0 * D4 + tid] = s0;
        cy[base + 1 * D4 + tid] = s1;
        cy[base + 2 * D4 + tid] = s2;

        const float* mt = Mtot + (size_t)(b * CC + c) * 6;
        const float p00 = mt[0], p10 = mt[1], p11 = mt[2];
        const float p20 = mt[3], p21 = mt[4], p22 = mt[5];

        const vf4 l0 = le[base + 0 * D4 + tid];
        const vf4 l1 = le[base + 1 * D4 + tid];
        const vf4 l2 = le[base + 2 * D4 + tid];

        const vf4 n0 = p00 * s0 + l0;
        const vf4 n1 = p10 * s0 + p11 * s1 + l1;
        const vf4 n2 = p20 * s0 + p21 * s1 + p22 * s2 + l2;
        s0 = n0; s1 = n1; s2 = n2;
    }

    if (h == 0) {
        bd[(size_t)(0 * BB + b) * D4 + tid] = s0;
        bd[(size_t)(1 * BB + b) * D4 + tid] = s1;
        bd[(size_t)(2 * BB + b) * D4 + tid] = s2;
    } else {
        // next_last_momentum (2,B,D) follows update in d_out
        const size_t nl = (size_t)BB * (NN + 1) * D4;
        __builtin_nontemporal_store(s0, &out4[nl + (size_t)(0 * BB + b) * D4 + tid]);
        __builtin_nontemporal_store(s1, &out4[nl + (size_t)(1 * BB + b) * D4 + tid]);
    }
}

// ---------------- Pass 3: rescan from exact carry (grad L3-hot), stream out ----------------
__global__ __launch_bounds__(128) void pass3_final(
    const float* __restrict__ grad,
    const float* __restrict__ am,
    const float* __restrict__ cm,
    const float* __restrict__ dec,
    const float* __restrict__ carry,
    float* __restrict__ out,
    int h)
{
    const int c = blockIdx.x + h * HC;
    const int b = blockIdx.y;
    const int tid = threadIdx.x;

    const vf4* cy = (const vf4*)carry;
    const size_t base = (size_t)(b * CC + c) * 3 * D4;
    vf4 m0 = cy[base + 0 * D4 + tid];
    vf4 m1 = cy[base + 1 * D4 + tid];
    vf4 w  = cy[base + 2 * D4 + tid];

    const float* a0p = am + (size_t)(0 * BB + b) * NN;
    const float* a1p = am + (size_t)(1 * BB + b) * NN;
    const float* c0p = cm + (size_t)(0 * BB + b) * NN;
    const float* c1p = cm + (size_t)(1 * BB + b) * NN;
    const float* c2p = cm + (size_t)(2 * BB + b) * NN;
    const float* dp  = dec + (size_t)b * NN;

    const vf4* g4 = (const vf4*)grad;
    vf4* out4 = (vf4*)out;

    const int t0 = c * LL;
    #pragma unroll 8
    for (int t = t0; t < t0 + LL; ++t) {
        const float a0 = a0p[t], a1 = a1p[t];
        const float c0 = c0p[t], c1 = c1p[t], c2 = c2p[t];
        const float e  = 1.0f - dp[t];
        const vf4 g = g4[(size_t)(b * NN + t) * D4 + tid];

        m0 = a0 * m0 + g;
        m1 = a1 * m1 + m0;
        w  = e * w + c0 * g + c1 * m0 + c2 * m1;

        __builtin_nontemporal_store(
            w, &out4[(size_t)(b * (NN + 1) + t + 1) * D4 + tid]);
    }
}

extern "C" void kernel_launch(void* const* d_in, const int* in_sizes, int n_in,
                              void* d_out, int out_size, void* d_ws, size_t ws_size,
                              hipStream_t stream) {
    const float* Wt   = (const float*)d_in[0];   // (B,D)
    // d_in[1] = x_t, unused
    const float* grad = (const float*)d_in[2];   // (B,N,D)
    const float* lm   = (const float*)d_in[3];   // (2,B,D)
    const float* am   = (const float*)d_in[4];   // (2,B,N,1)
    const float* cm   = (const float*)d_in[5];   // (3,B,N)
    const float* dec  = (const float*)d_in[6];   // (B,N,1)
    float* out = (float*)d_out;

    // ws: Mtot 48KB | local_end 12.6MB | carry 12.6MB | boundary 192KB
    char* ws = (char*)d_ws;
    float* Mtot      = (float*)ws;
    float* local_end = (float*)(ws + (size_t)BB * CC * 6 * sizeof(float));
    float* carry     = local_end + (size_t)BB * CC * 3 * DD;
    float* boundary  = carry + (size_t)BB * CC * 3 * DD;

    dim3 gridA(HC, BB);
    for (int h = 0; h < 2; ++h) {
        pass1_local<<<gridA, 128, 0, stream>>>(grad, am, cm, dec, Mtot, local_end, h);
        pass2_carry<<<BB, 128, 0, stream>>>(Wt, lm, Mtot, local_end, carry,
                                            boundary, out, h);
        pass3_final<<<gridA, 128, 0, stream>>>(grad, am, cm, dec, carry, out, h);
    }
}

// Round 7
// 89.167 us; speedup vs baseline: 7.0436x; 1.0591x over previous
//
#include <hip/hip_runtime.h>

// Problem constants: B=32, N=2048, D=512, O=2
#define BB 32
#define NN 2048
#define DD 512
#define CC 64            // chunks along N (global)
#define LL 32            // steps per chunk
#define HC 32            // chunks per half
#define DV 256           // vf2 lanes per row (512/2)

typedef float vf2 __attribute__((ext_vector_type(2)));

// Recurrence: m0'=a0*m0+g ; m1'=a1*m1+m0' ; w'=e*w + c0*g + c1*m0' + c2*m1'
// Chunk matrix P = prod M_t (lower-tri, gate-only, 6 scalars).

// ---------------- A: per-chunk local scan (zero init) + chunk matrix, one half ----------------
__global__ __launch_bounds__(256) void pass1_half(
    const float* __restrict__ grad,   // (B,N,D)
    const float* __restrict__ am,     // (2,B,N)
    const float* __restrict__ cm,     // (3,B,N)
    const float* __restrict__ dec,    // (B,N)
    float* __restrict__ Mtot,         // (B,CC,6)
    float* __restrict__ local_end,    // (B,CC,3,D)
    int h)
{
    const int c = h * HC + blockIdx.x;
    const int b = blockIdx.y;
    const int tid = threadIdx.x;      // vf2 lane; d = 2*tid
    const vf2* g2 = (const vf2*)grad;

    const float* a0p = am + (size_t)(0 * BB + b) * NN;
    const float* a1p = am + (size_t)(1 * BB + b) * NN;
    const float* c0p = cm + (size_t)(0 * BB + b) * NN;
    const float* c1p = cm + (size_t)(1 * BB + b) * NN;
    const float* c2p = cm + (size_t)(2 * BB + b) * NN;
    const float* dp  = dec + (size_t)b * NN;

    vf2 m0 = {0.f, 0.f}, m1 = m0, w = m0;
    float p00 = 1.f, p10 = 0.f, p11 = 1.f, p20 = 0.f, p21 = 0.f, p22 = 1.f;

    const int t0 = c * LL;
    #pragma unroll 8
    for (int t = t0; t < t0 + LL; ++t) {
        const float a0 = a0p[t], a1 = a1p[t];
        const float c0 = c0p[t], c1 = c1p[t], c2 = c2p[t];
        const float e  = 1.0f - dp[t];
        const vf2 g = g2[(size_t)(b * NN + t) * DV + tid];   // plain load -> allocates L3

        m0 = a0 * m0 + g;
        m1 = a1 * m1 + m0;
        w  = e * w + c0 * g + c1 * m0 + c2 * m1;

        const float k0 = (c1 + c2) * a0;
        const float k1 = c2 * a1;
        const float n00 = a0 * p00;
        const float n10 = fmaf(a0, p00, a1 * p10);
        const float n11 = a1 * p11;
        const float n20 = fmaf(k0, p00, fmaf(k1, p10, e * p20));
        const float n21 = fmaf(k1, p11, e * p21);
        const float n22 = e * p22;
        p00 = n00; p10 = n10; p11 = n11; p20 = n20; p21 = n21; p22 = n22;
    }

    vf2* le = (vf2*)local_end;
    const size_t base = (size_t)(b * CC + c) * 3 * DV;
    le[base + 0 * DV + tid] = m0;
    le[base + 1 * DV + tid] = m1;
    le[base + 2 * DV + tid] = w;

    if (tid == 0) {
        float* mt = Mtot + (size_t)(b * CC + c) * 6;
        mt[0] = p00; mt[1] = p10; mt[2] = p11;
        mt[3] = p20; mt[4] = p21; mt[5] = p22;
    }
}

// ---------------- B: redundant carry-prefix + final rescan (grad L3-hot), one half ----------------
__global__ __launch_bounds__(256) void pass3_half(
    const float* __restrict__ grad,
    const float* __restrict__ am,
    const float* __restrict__ cm,
    const float* __restrict__ dec,
    const float* __restrict__ Wt,        // (B,D)
    const float* __restrict__ lm,        // (2,B,D)
    const float* __restrict__ Mtot,      // (B,CC,6)
    const float* __restrict__ local_end, // (B,CC,3,D)
    float* __restrict__ boundary,        // (3,B,D) inter-half state
    float* __restrict__ out,             // update (B,N+1,D) then next_last (2,B,D)
    int h)
{
    const int bx = blockIdx.x;
    const int c  = h * HC + bx;
    const int b  = blockIdx.y;
    const int tid = threadIdx.x;

    // ---- base state for this half ----
    vf2 s0, s1, s2;
    if (h == 0) {
        s0 = ((const vf2*)lm)[(size_t)(0 * BB + b) * DV + tid];
        s1 = ((const vf2*)lm)[(size_t)(1 * BB + b) * DV + tid];
        s2 = ((const vf2*)Wt)[(size_t)b * DV + tid];
    } else {
        const vf2* bd = (const vf2*)boundary;
        s0 = bd[(size_t)(0 * BB + b) * DV + tid];
        s1 = bd[(size_t)(1 * BB + b) * DV + tid];
        s2 = bd[(size_t)(2 * BB + b) * DV + tid];
    }

    // ---- redundant prefix over this half's preceding chunks (loads all independent) ----
    const vf2* le = (const vf2*)local_end;
    for (int cc = h * HC; cc < c; ++cc) {
        const float* mt = Mtot + (size_t)(b * CC + cc) * 6;
        const float p00 = mt[0], p10 = mt[1], p11 = mt[2];
        const float p20 = mt[3], p21 = mt[4], p22 = mt[5];

        const size_t base = (size_t)(b * CC + cc) * 3 * DV;
        const vf2 l0 = le[base + 0 * DV + tid];
        const vf2 l1 = le[base + 1 * DV + tid];
        const vf2 l2 = le[base + 2 * DV + tid];

        const vf2 n0 = p00 * s0 + l0;
        const vf2 n1 = p10 * s0 + p11 * s1 + l1;
        const vf2 n2 = p20 * s0 + p21 * s1 + p22 * s2 + l2;
        s0 = n0; s1 = n1; s2 = n2;
    }

    vf2* out2 = (vf2*)out;
    if (h == 0 && bx == 0) {
        // update[b][0][:] = W_t (s2 here)
        __builtin_nontemporal_store(s2, &out2[(size_t)(b * (NN + 1)) * DV + tid]);
    }

    // ---- final rescan from exact carry; grad should be L3-resident from pass A ----
    const float* a0p = am + (size_t)(0 * BB + b) * NN;
    const float* a1p = am + (size_t)(1 * BB + b) * NN;
    const float* c0p = cm + (size_t)(0 * BB + b) * NN;
    const float* c1p = cm + (size_t)(1 * BB + b) * NN;
    const float* c2p = cm + (size_t)(2 * BB + b) * NN;
    const float* dp  = dec + (size_t)b * NN;

    const vf2* g2 = (const vf2*)grad;
    vf2 m0 = s0, m1 = s1, w = s2;

    const int t0 = c * LL;
    #pragma unroll 8
    for (int t = t0; t < t0 + LL; ++t) {
        const float a0 = a0p[t], a1 = a1p[t];
        const float c0 = c0p[t], c1 = c1p[t], c2 = c2p[t];
        const float e  = 1.0f - dp[t];
        const vf2 g = g2[(size_t)(b * NN + t) * DV + tid];   // plain load -> L3 hit

        m0 = a0 * m0 + g;
        m1 = a1 * m1 + m0;
        w  = e * w + c0 * g + c1 * m0 + c2 * m1;

        // NT store: no L3 allocation -> doesn't evict grad
        __builtin_nontemporal_store(
            w, &out2[(size_t)(b * (NN + 1) + t + 1) * DV + tid]);
    }

    if (bx == HC - 1) {
        if (h == 0) {
            vf2* bd = (vf2*)boundary;
            bd[(size_t)(0 * BB + b) * DV + tid] = m0;
            bd[(size_t)(1 * BB + b) * DV + tid] = m1;
            bd[(size_t)(2 * BB + b) * DV + tid] = w;
        } else {
            // next_last_momentum (2,B,D) = final (m0, m1)
            const size_t nl = (size_t)BB * (NN + 1) * DV;
            __builtin_nontemporal_store(m0, &out2[nl + (size_t)(0 * BB + b) * DV + tid]);
            __builtin_nontemporal_store(m1, &out2[nl + (size_t)(1 * BB + b) * DV + tid]);
        }
    }
}

extern "C" void kernel_launch(void* const* d_in, const int* in_sizes, int n_in,
                              void* d_out, int out_size, void* d_ws, size_t ws_size,
                              hipStream_t stream) {
    const float* Wt   = (const float*)d_in[0];   // (B,D)
    // d_in[1] = x_t, unused
    const float* grad = (const float*)d_in[2];   // (B,N,D)
    const float* lm   = (const float*)d_in[3];   // (2,B,D)
    const float* am   = (const float*)d_in[4];   // (2,B,N,1)
    const float* cm   = (const float*)d_in[5];   // (3,B,N)
    const float* dec  = (const float*)d_in[6];   // (B,N,1)
    float* out = (float*)d_out;

    // ws: Mtot 48KB | local_end 12.6MB | boundary 192KB
    char* ws = (char*)d_ws;
    float* Mtot      = (float*)ws;
    float* local_end = (float*)(ws + (size_t)BB * CC * 6 * sizeof(float));
    float* boundary  = local_end + (size_t)BB * CC * 3 * DD;

    dim3 grid(HC, BB);
    for (int h = 0; h < 2; ++h) {
        pass1_half<<<grid, 256, 0, stream>>>(grad, am, cm, dec, Mtot, local_end, h);
        pass3_half<<<grid, 256, 0, stream>>>(grad, am, cm, dec, Wt, lm, Mtot,
                                             local_end, boundary, out, h);
    }
}